// Round 3
// baseline (5230.621 us; speedup 1.0000x reference)
//
#include <hip/hip_runtime.h>

#define BB 4
#define TT 12
#define NN 10000
#define DD 2
#define EE 320000
#define HH 64
#define NPREDD 12
#define TD 24

__device__ __forceinline__ float bcast(float v, int j) {
    return __int_as_float(__builtin_amdgcn_readlane(__float_as_int(v), j));
}

// ---------------- CSR build (keyed by dst; gather from src) ----------------
__global__ void hist_kernel(const int* __restrict__ dstv, int* __restrict__ deg) {
    int e = blockIdx.x*256 + threadIdx.x;
    if (e < EE) atomicAdd(&deg[dstv[e]], 1);
}

__global__ void scan_kernel(const int* __restrict__ deg, int* __restrict__ row_ptr,
                            int* __restrict__ cursor) {
    __shared__ int part[1024];
    int tid = threadIdx.x;
    const int CH = 10;
    int start = tid*CH;
    int s = 0;
    if (start < NN)
        for (int i=0;i<CH;i++) s += deg[start+i];
    part[tid] = s;
    __syncthreads();
    if (tid == 0) {
        int acc = 0;
        for (int i=0;i<1024;i++){ int v=part[i]; part[i]=acc; acc+=v; }
        row_ptr[NN] = acc;
    }
    __syncthreads();
    if (start < NN) {
        int acc = part[tid];
        for (int i=0;i<CH;i++){ int idx=start+i; row_ptr[idx]=acc; cursor[idx]=acc; acc+=deg[idx]; }
    }
}

__global__ void fill_kernel(const int* __restrict__ srcv, const int* __restrict__ dstv,
                            const float* __restrict__ ew, int* __restrict__ cursor,
                            int2* __restrict__ csr) {
    int e = blockIdx.x*256 + threadIdx.x;
    if (e < EE) {
        int d = dstv[e];
        int pos = atomicAdd(&cursor[d], 1);
        csr[pos] = make_int2(srcv[e], __float_as_int(ew[e]));
    }
}

// ---------------- x transpose: [B,T,N,D] -> [N][T*D][B] (batch fastest) ----------------
__global__ void transpose_x(const float* __restrict__ x, float* __restrict__ xTb) {
    int idx = blockIdx.x*256 + threadIdx.x;
    if (idx >= BB*TT*NN*DD) return;
    int d = idx & 1;
    int n = (idx >> 1) % NN;
    int t = (idx / (NN*DD)) % TT;
    int b = idx / (TT*NN*DD);
    xTb[((size_t)n*TD + (t*DD + d))*BB + b] = x[idx];
}

// ---------------- AX = A @ x_t for all t,b at once; layout [N][TD][B] ----------------
__global__ __launch_bounds__(256)
void ax_gather(const float* __restrict__ xTb, const int* __restrict__ row_ptr,
               const int2* __restrict__ csr, float* __restrict__ AXb) {
    int gw = (blockIdx.x*256 + threadIdx.x) >> 6;
    if (gw >= NN) return;
    int n = gw;
    int lane = threadIdx.x & 63;
    int half = lane >> 5;       // edge e+half
    int c = lane & 31;          // ch index (0..23 useful)
    float4 acc = {0.f,0.f,0.f,0.f};
    int e0 = row_ptr[n], e1 = row_ptr[n+1];
    for (int e = e0; e < e1; e += 2) {
        int idx = e + half;
        int2 cw = csr[idx];                       // idx <= e1 <= EE (padded+zeroed)
        float w = (idx < e1) ? __int_as_float(cw.y) : 0.f;
        const float4 v = *(const float4*)(xTb + (size_t)cw.x*(TD*BB) + c*4);
        acc.x = fmaf(w, v.x, acc.x); acc.y = fmaf(w, v.y, acc.y);
        acc.z = fmaf(w, v.z, acc.z); acc.w = fmaf(w, v.w, acc.w);
    }
    acc.x += __shfl_xor(acc.x, 32); acc.y += __shfl_xor(acc.y, 32);
    acc.z += __shfl_xor(acc.z, 32); acc.w += __shfl_xor(acc.w, 32);
    if (lane < TD) *(float4*)(AXb + (size_t)n*(TD*BB) + lane*4) = acc;
}

// ---------------- W1sum[k] = W1[k][:64] + W1[k][64:] ----------------
__global__ void w1sum_kernel(const float* __restrict__ W1, float* __restrict__ W1s) {
    int i = blockIdx.x*256 + threadIdx.x;
    if (i < 8192) {
        int k = i >> 12, r = (i >> 6) & 63, c = i & 63;
        W1s[i] = W1[(k*128 + r)*64 + c] + W1[(k*128 + 64 + r)*64 + c];
    }
}

// ---------------- fused layer ----------------
// 1024 threads = 16 waves, 2 rows/wave -> 32 rows/block
template<int L0>
__global__ __launch_bounds__(1024, 8)
void layer_kernel(const float* __restrict__ h_in,
                  const float* __restrict__ x,
                  const float* __restrict__ AXb,
                  const float* __restrict__ W,
                  const float* __restrict__ bias,
                  const int* __restrict__ row_ptr,
                  const int2* __restrict__ csr,
                  float* __restrict__ h_out,
                  int t)
{
    __shared__ float sWa[4096];   // [j][out]
    __shared__ float sWb[4096];   // [j][out]
    __shared__ float sWx[256];
    __shared__ float sBias[64];

    int tid = threadIdx.x;
    if (L0) {
        for (int i=tid; i<4096; i+=1024) { sWa[i] = W[128+i]; sWb[i] = W[4352+i]; }
        if (tid < 128) { sWx[tid] = W[tid]; sWx[128+tid] = W[4224+tid]; }
    } else {
        for (int i=tid; i<4096; i+=1024) { sWa[i] = W[i]; sWb[i] = W[4096+i]; }
    }
    if (tid < 64) sBias[tid] = bias[tid];
    __syncthreads();

    int wave = tid >> 6, lane = tid & 63;
    int g = lane >> 4, c = lane & 15;
    int b = blockIdx.x & 3;          // batch -> one XCD serves one batch's h in L2
    int chunk = blockIdx.x >> 2;     // 0..312
    const float* hb = h_in + (size_t)b*NN*HH;
    float* ho = h_out + (size_t)b*NN*HH;
    int n0 = chunk*32 + wave*2;

    float4 hv4[2], ac4[2];
    #pragma unroll
    for (int i=0;i<2;i++) {
        int n = n0 + i;
        int nn = n < NN ? n : NN-1;
        hv4[i] = *(const float4*)(hb + (size_t)nn*HH + c*4);
        float4 acc = {0.f,0.f,0.f,0.f};
        int e0 = row_ptr[nn], e1 = row_ptr[nn+1];
        for (int e = e0; e < e1; e += 8) {
            int i0 = e + 2*g;                       // group's 2 edges
            int2 cw0 = csr[i0];                     // <= EE+6, padded+zeroed
            int2 cw1 = csr[i0+1];
            float w0 = (i0   < e1) ? __int_as_float(cw0.y) : 0.f;
            float w1 = (i0+1 < e1) ? __int_as_float(cw1.y) : 0.f;
            const float4 v0 = *(const float4*)(hb + (size_t)cw0.x*HH + c*4);
            const float4 v1 = *(const float4*)(hb + (size_t)cw1.x*HH + c*4);
            acc.x = fmaf(w0, v0.x, acc.x); acc.y = fmaf(w0, v0.y, acc.y);
            acc.z = fmaf(w0, v0.z, acc.z); acc.w = fmaf(w0, v0.w, acc.w);
            acc.x = fmaf(w1, v1.x, acc.x); acc.y = fmaf(w1, v1.y, acc.y);
            acc.z = fmaf(w1, v1.z, acc.z); acc.w = fmaf(w1, v1.w, acc.w);
        }
        acc.x += __shfl_xor(acc.x, 16); acc.y += __shfl_xor(acc.y, 16);
        acc.z += __shfl_xor(acc.z, 16); acc.w += __shfl_xor(acc.w, 16);
        acc.x += __shfl_xor(acc.x, 32); acc.y += __shfl_xor(acc.y, 32);
        acc.z += __shfl_xor(acc.z, 32); acc.w += __shfl_xor(acc.w, 32);
        ac4[i] = acc;
    }

    float out[2];
    #pragma unroll
    for (int i=0;i<2;i++) out[i] = sBias[lane];
    if (L0) {
        #pragma unroll
        for (int i=0;i<2;i++) {
            int n = n0 + i;
            int nn = n < NN ? n : NN-1;
            const float2 xv = *(const float2*)(x + (((size_t)b*TT + t)*NN + nn)*DD);
            float ax0 = AXb[(size_t)nn*(TD*BB) + (2*t)*BB + b];
            float ax1 = AXb[(size_t)nn*(TD*BB) + (2*t+1)*BB + b];
            out[i] += xv.x*sWx[lane] + xv.y*sWx[64+lane]
                    + ax0*sWx[128+lane] + ax1*sWx[192+lane];
        }
    }

    // GEMM: channel quad q held by lane q; readlane broadcasts (imm lane index)
    #pragma unroll
    for (int q=0; q<16; ++q) {
        float wa0 = sWa[(4*q+0)*64 + lane], wa1 = sWa[(4*q+1)*64 + lane];
        float wa2 = sWa[(4*q+2)*64 + lane], wa3 = sWa[(4*q+3)*64 + lane];
        float wb0 = sWb[(4*q+0)*64 + lane], wb1 = sWb[(4*q+1)*64 + lane];
        float wb2 = sWb[(4*q+2)*64 + lane], wb3 = sWb[(4*q+3)*64 + lane];
        #pragma unroll
        for (int i=0;i<2;i++) {
            out[i] = fmaf(bcast(hv4[i].x, q), wa0, out[i]);
            out[i] = fmaf(bcast(hv4[i].y, q), wa1, out[i]);
            out[i] = fmaf(bcast(hv4[i].z, q), wa2, out[i]);
            out[i] = fmaf(bcast(hv4[i].w, q), wa3, out[i]);
            out[i] = fmaf(bcast(ac4[i].x, q), wb0, out[i]);
            out[i] = fmaf(bcast(ac4[i].y, q), wb1, out[i]);
            out[i] = fmaf(bcast(ac4[i].z, q), wb2, out[i]);
            out[i] = fmaf(bcast(ac4[i].w, q), wb3, out[i]);
        }
    }

    #pragma unroll
    for (int i=0;i<2;i++) {
        int n = n0 + i;
        if (n < NN) ho[(size_t)n*HH + lane] = fmaxf(out[i], 0.f);
    }
}

// ---------------- output ----------------
__global__ void out_kernel(const float* __restrict__ h, const float* __restrict__ Wp,
                           const float* __restrict__ bp, float* __restrict__ outp) {
    int g = blockIdx.x*256 + threadIdx.x;
    int wave = g >> 6, lane = g & 63;
    if (wave >= BB*NN) return;
    int b = wave / NN, n = wave - b*NN;
    float v = h[(size_t)wave*HH + lane] * Wp[lane];
    for (int off=32; off; off>>=1) v += __shfl_down(v, off);
    v = __shfl(v, 0) + bp[0];
    if (lane < NPREDD) outp[((size_t)b*NPREDD + lane)*NN + n] = v;
}

extern "C" void kernel_launch(void* const* d_in, const int* in_sizes, int n_in,
                              void* d_out, int out_size, void* d_ws, size_t ws_size,
                              hipStream_t stream) {
    const float* x   = (const float*)d_in[0];
    const int*   ei  = (const int*)d_in[1];
    const float* ew  = (const float*)d_in[2];
    const float* W0  = (const float*)d_in[3];
    const float* b0  = (const float*)d_in[4];
    const float* W1  = (const float*)d_in[5];
    const float* b1  = (const float*)d_in[6];
    const float* Wp  = (const float*)d_in[7];
    const float* bp  = (const float*)d_in[8];
    float* outp = (float*)d_out;

    char* ws = (char*)d_ws;
    size_t off = 0;
    auto alloc = [&](size_t bytes) { void* p = ws + off; off = (off + bytes + 255) & ~(size_t)255; return p; };
    float* h    = (float*)alloc((size_t)BB*NN*HH*4);
    float* h1   = (float*)alloc((size_t)BB*NN*HH*4);
    float* xTb  = (float*)alloc(((size_t)NN*TD*BB + 64)*4);     // +64 pad for ragged f4 reads
    float* AXb  = (float*)alloc((size_t)NN*TD*BB*4);
    float* W1s  = (float*)alloc(2*64*64*4);
    int2*  csr  = (int2*)alloc(((size_t)EE + 16)*8);            // +16 zeroed pad entries
    int* row_ptr= (int*)alloc((NN+1)*4);
    int* deg    = (int*)alloc(NN*4);
    int* cursor = (int*)alloc(NN*4);

    const int* srcv = ei;
    const int* dstv = ei + EE;

    hipMemsetAsync(deg, 0, NN*4, stream);
    hipMemsetAsync(h, 0, (size_t)BB*NN*HH*4, stream);
    hipMemsetAsync(csr + EE, 0, 16*8, stream);

    hist_kernel<<<(EE+255)/256, 256, 0, stream>>>(dstv, deg);
    scan_kernel<<<1, 1024, 0, stream>>>(deg, row_ptr, cursor);
    fill_kernel<<<(EE+255)/256, 256, 0, stream>>>(srcv, dstv, ew, cursor, csr);
    transpose_x<<<(BB*TT*NN*DD+255)/256, 256, 0, stream>>>(x, xTb);
    ax_gather<<<(NN*64+255)/256, 256, 0, stream>>>(xTb, row_ptr, csr, AXb);
    w1sum_kernel<<<32, 256, 0, stream>>>(W1, W1s);

    const int grid = 313*4;   // 32 rows/block, 4 batches
    for (int t=0; t<TT; ++t) {
        layer_kernel<1><<<grid, 1024, 0, stream>>>(h,  x, AXb, W0,  b0, row_ptr, csr, h1, t);
        layer_kernel<0><<<grid, 1024, 0, stream>>>(h1, nullptr, nullptr, W1s, b1, row_ptr, csr, h, 0);
    }
    out_kernel<<<(BB*NN*64+255)/256, 256, 0, stream>>>(h, Wp, bp, outp);
}

// Round 4
// 1221.017 us; speedup vs baseline: 4.2838x; 4.2838x over previous
//
#include <hip/hip_runtime.h>

#define BB 4
#define TT 12
#define NN 10000
#define DD 2
#define EE 320000
#define HH 64
#define NPREDD 12
#define TD 24

__device__ __forceinline__ float bcast(float v, int j) {
    return __int_as_float(__builtin_amdgcn_readlane(__float_as_int(v), j));
}

// ---------------- CSR build (keyed by dst; gather from src) ----------------
__global__ void hist_kernel(const int* __restrict__ dstv, int* __restrict__ deg) {
    int e = blockIdx.x*256 + threadIdx.x;
    if (e < EE) atomicAdd(&deg[dstv[e]], 1);
}

__global__ void scan_kernel(const int* __restrict__ deg, int* __restrict__ row_ptr,
                            int* __restrict__ cursor) {
    __shared__ int part[1024];
    int tid = threadIdx.x;
    const int CH = 10;
    int start = tid*CH;
    int s = 0;
    if (start < NN)
        for (int i=0;i<CH;i++) s += deg[start+i];
    part[tid] = s;
    __syncthreads();
    if (tid == 0) {
        int acc = 0;
        for (int i=0;i<1024;i++){ int v=part[i]; part[i]=acc; acc+=v; }
        row_ptr[NN] = acc;
    }
    __syncthreads();
    if (start < NN) {
        int acc = part[tid];
        for (int i=0;i<CH;i++){ int idx=start+i; row_ptr[idx]=acc; cursor[idx]=acc; acc+=deg[idx]; }
    }
}

__global__ void fill_kernel(const int* __restrict__ srcv, const int* __restrict__ dstv,
                            const float* __restrict__ ew, int* __restrict__ cursor,
                            int2* __restrict__ csr) {
    int e = blockIdx.x*256 + threadIdx.x;
    if (e < EE) {
        int d = dstv[e];
        int pos = atomicAdd(&cursor[d], 1);
        csr[pos] = make_int2(srcv[e], __float_as_int(ew[e]));
    }
}

// ---------------- x transpose: [B,T,N,D] -> [N][T*D][B] (batch fastest) ----------------
__global__ void transpose_x(const float* __restrict__ x, float* __restrict__ xTb) {
    int idx = blockIdx.x*256 + threadIdx.x;
    if (idx >= BB*TT*NN*DD) return;
    int d = idx & 1;
    int n = (idx >> 1) % NN;
    int t = (idx / (NN*DD)) % TT;
    int b = idx / (TT*NN*DD);
    xTb[((size_t)n*TD + (t*DD + d))*BB + b] = x[idx];
}

// ---------------- AX = A @ x_t for all t,b at once; layout [N][TD][B] ----------------
__global__ __launch_bounds__(256)
void ax_gather(const float* __restrict__ xTb, const int* __restrict__ row_ptr,
               const int2* __restrict__ csr, float* __restrict__ AXb) {
    int gw = (blockIdx.x*256 + threadIdx.x) >> 6;
    if (gw >= NN) return;
    int n = gw;
    int lane = threadIdx.x & 63;
    int half = lane >> 5;       // edge e+half
    int c = lane & 31;          // f4-chunk index (0..23 useful of row's 24)
    float4 acc = {0.f,0.f,0.f,0.f};
    int e0 = row_ptr[n], e1 = row_ptr[n+1];
    for (int e = e0; e < e1; e += 4) {
        int ia = e + half;
        int ib = e + 2 + half;
        int2 ca = csr[ia];                        // pad-safe (csr has 16 zeroed tail)
        int2 cb = csr[ib];
        float wa = (ia < e1) ? __int_as_float(ca.y) : 0.f;
        float wb = (ib < e1) ? __int_as_float(cb.y) : 0.f;
        const float4 va = *(const float4*)(xTb + (size_t)ca.x*(TD*BB) + c*4);
        const float4 vb = *(const float4*)(xTb + (size_t)cb.x*(TD*BB) + c*4);
        acc.x = fmaf(wa, va.x, acc.x); acc.y = fmaf(wa, va.y, acc.y);
        acc.z = fmaf(wa, va.z, acc.z); acc.w = fmaf(wa, va.w, acc.w);
        acc.x = fmaf(wb, vb.x, acc.x); acc.y = fmaf(wb, vb.y, acc.y);
        acc.z = fmaf(wb, vb.z, acc.z); acc.w = fmaf(wb, vb.w, acc.w);
    }
    acc.x += __shfl_xor(acc.x, 32); acc.y += __shfl_xor(acc.y, 32);
    acc.z += __shfl_xor(acc.z, 32); acc.w += __shfl_xor(acc.w, 32);
    if (lane < TD) *(float4*)(AXb + (size_t)n*(TD*BB) + lane*4) = acc;
}

// ---------------- W1sum[k] = W1[k][:64] + W1[k][64:] ----------------
__global__ void w1sum_kernel(const float* __restrict__ W1, float* __restrict__ W1s) {
    int i = blockIdx.x*256 + threadIdx.x;
    if (i < 8192) {
        int k = i >> 12, r = (i >> 6) & 63, c = i & 63;
        W1s[i] = W1[(k*128 + r)*64 + c] + W1[(k*128 + 64 + r)*64 + c];
    }
}

// ---------------- fused layer ----------------
// 512 threads = 8 waves, 2 rows/wave -> 16 rows/block
template<int L0>
__global__ __launch_bounds__(512, 6)
void layer_kernel(const float* __restrict__ h_in,
                  const float* __restrict__ x,
                  const float* __restrict__ AXb,
                  const float* __restrict__ W,
                  const float* __restrict__ bias,
                  const int* __restrict__ row_ptr,
                  const int2* __restrict__ csr,
                  float* __restrict__ h_out,
                  int t)
{
    __shared__ float sWa[4096];   // [j][out]
    __shared__ float sWb[4096];   // [j][out]
    __shared__ float sWx[256];
    __shared__ float sBias[64];

    int tid = threadIdx.x;
    if (L0) {
        for (int i=tid; i<4096; i+=512) { sWa[i] = W[128+i]; sWb[i] = W[4352+i]; }
        if (tid < 128) { sWx[tid] = W[tid]; sWx[128+tid] = W[4224+tid]; }
    } else {
        for (int i=tid; i<4096; i+=512) { sWa[i] = W[i]; sWb[i] = W[4096+i]; }
    }
    if (tid < 64) sBias[tid] = bias[tid];
    __syncthreads();

    int wave = tid >> 6, lane = tid & 63;
    int g = lane >> 4, c = lane & 15;
    int b = blockIdx.x & 3;          // batch -> XCD pairing keeps gather set in L2
    int chunk = blockIdx.x >> 2;     // 0..624
    const float* hb = h_in + (size_t)b*NN*HH;
    float* ho = h_out + (size_t)b*NN*HH;
    int n0 = chunk*16 + wave*2;      // 625*16 == 10000, exact

    float4 hv4[2], ac4[2];
    #pragma unroll
    for (int i=0;i<2;i++) {
        int n = n0 + i;
        hv4[i] = *(const float4*)(hb + (size_t)n*HH + c*4);
        float4 acc = {0.f,0.f,0.f,0.f};
        int e0 = row_ptr[n], e1 = row_ptr[n+1];
        for (int e = e0; e < e1; e += 8) {
            int i0 = e + 2*g;                       // group's 2 edges
            int2 cw0 = csr[i0];                     // pad-safe
            int2 cw1 = csr[i0+1];
            float w0 = (i0   < e1) ? __int_as_float(cw0.y) : 0.f;
            float w1 = (i0+1 < e1) ? __int_as_float(cw1.y) : 0.f;
            const float4 v0 = *(const float4*)(hb + (size_t)cw0.x*HH + c*4);
            const float4 v1 = *(const float4*)(hb + (size_t)cw1.x*HH + c*4);
            acc.x = fmaf(w0, v0.x, acc.x); acc.y = fmaf(w0, v0.y, acc.y);
            acc.z = fmaf(w0, v0.z, acc.z); acc.w = fmaf(w0, v0.w, acc.w);
            acc.x = fmaf(w1, v1.x, acc.x); acc.y = fmaf(w1, v1.y, acc.y);
            acc.z = fmaf(w1, v1.z, acc.z); acc.w = fmaf(w1, v1.w, acc.w);
        }
        acc.x += __shfl_xor(acc.x, 16); acc.y += __shfl_xor(acc.y, 16);
        acc.z += __shfl_xor(acc.z, 16); acc.w += __shfl_xor(acc.w, 16);
        acc.x += __shfl_xor(acc.x, 32); acc.y += __shfl_xor(acc.y, 32);
        acc.z += __shfl_xor(acc.z, 32); acc.w += __shfl_xor(acc.w, 32);
        ac4[i] = acc;
    }

    float out[2];
    #pragma unroll
    for (int i=0;i<2;i++) out[i] = sBias[lane];
    if (L0) {
        #pragma unroll
        for (int i=0;i<2;i++) {
            int n = n0 + i;
            const float2 xv = *(const float2*)(x + (((size_t)b*TT + t)*NN + n)*DD);
            float ax0 = AXb[(size_t)n*(TD*BB) + (2*t)*BB + b];
            float ax1 = AXb[(size_t)n*(TD*BB) + (2*t+1)*BB + b];
            out[i] += xv.x*sWx[lane] + xv.y*sWx[64+lane]
                    + ax0*sWx[128+lane] + ax1*sWx[192+lane];
        }
    }

    // GEMM: channel quad q lives in lane q (g==0); readlane broadcast (imm index)
    #pragma unroll
    for (int q=0; q<16; ++q) {
        float wa0 = sWa[(4*q+0)*64 + lane], wa1 = sWa[(4*q+1)*64 + lane];
        float wa2 = sWa[(4*q+2)*64 + lane], wa3 = sWa[(4*q+3)*64 + lane];
        float wb0 = sWb[(4*q+0)*64 + lane], wb1 = sWb[(4*q+1)*64 + lane];
        float wb2 = sWb[(4*q+2)*64 + lane], wb3 = sWb[(4*q+3)*64 + lane];
        #pragma unroll
        for (int i=0;i<2;i++) {
            out[i] = fmaf(bcast(hv4[i].x, q), wa0, out[i]);
            out[i] = fmaf(bcast(hv4[i].y, q), wa1, out[i]);
            out[i] = fmaf(bcast(hv4[i].z, q), wa2, out[i]);
            out[i] = fmaf(bcast(hv4[i].w, q), wa3, out[i]);
            out[i] = fmaf(bcast(ac4[i].x, q), wb0, out[i]);
            out[i] = fmaf(bcast(ac4[i].y, q), wb1, out[i]);
            out[i] = fmaf(bcast(ac4[i].z, q), wb2, out[i]);
            out[i] = fmaf(bcast(ac4[i].w, q), wb3, out[i]);
        }
    }

    #pragma unroll
    for (int i=0;i<2;i++)
        ho[(size_t)(n0+i)*HH + lane] = fmaxf(out[i], 0.f);
}

// ---------------- output ----------------
__global__ void out_kernel(const float* __restrict__ h, const float* __restrict__ Wp,
                           const float* __restrict__ bp, float* __restrict__ outp) {
    int g = blockIdx.x*256 + threadIdx.x;
    int wave = g >> 6, lane = g & 63;
    if (wave >= BB*NN) return;
    int b = wave / NN, n = wave - b*NN;
    float v = h[(size_t)wave*HH + lane] * Wp[lane];
    for (int off=32; off; off>>=1) v += __shfl_down(v, off);
    v = __shfl(v, 0) + bp[0];
    if (lane < NPREDD) outp[((size_t)b*NPREDD + lane)*NN + n] = v;
}

extern "C" void kernel_launch(void* const* d_in, const int* in_sizes, int n_in,
                              void* d_out, int out_size, void* d_ws, size_t ws_size,
                              hipStream_t stream) {
    const float* x   = (const float*)d_in[0];
    const int*   ei  = (const int*)d_in[1];
    const float* ew  = (const float*)d_in[2];
    const float* W0  = (const float*)d_in[3];
    const float* b0  = (const float*)d_in[4];
    const float* W1  = (const float*)d_in[5];
    const float* b1  = (const float*)d_in[6];
    const float* Wp  = (const float*)d_in[7];
    const float* bp  = (const float*)d_in[8];
    float* outp = (float*)d_out;

    char* ws = (char*)d_ws;
    size_t off = 0;
    auto alloc = [&](size_t bytes) { void* p = ws + off; off = (off + bytes + 255) & ~(size_t)255; return p; };
    float* h    = (float*)alloc((size_t)BB*NN*HH*4);
    float* h1   = (float*)alloc((size_t)BB*NN*HH*4);
    float* xTb  = (float*)alloc(((size_t)NN*TD*BB + 64)*4);     // +64 pad for ragged f4 reads
    float* AXb  = (float*)alloc((size_t)NN*TD*BB*4);
    float* W1s  = (float*)alloc(2*64*64*4);
    int2*  csr  = (int2*)alloc(((size_t)EE + 16)*8);            // +16 zeroed pad entries
    int* row_ptr= (int*)alloc((NN+1)*4);
    int* deg    = (int*)alloc(NN*4);
    int* cursor = (int*)alloc(NN*4);

    const int* srcv = ei;
    const int* dstv = ei + EE;

    hipMemsetAsync(deg, 0, NN*4, stream);
    hipMemsetAsync(h, 0, (size_t)BB*NN*HH*4, stream);
    hipMemsetAsync(csr + EE, 0, 16*8, stream);

    hist_kernel<<<(EE+255)/256, 256, 0, stream>>>(dstv, deg);
    scan_kernel<<<1, 1024, 0, stream>>>(deg, row_ptr, cursor);
    fill_kernel<<<(EE+255)/256, 256, 0, stream>>>(srcv, dstv, ew, cursor, csr);
    transpose_x<<<(BB*TT*NN*DD+255)/256, 256, 0, stream>>>(x, xTb);
    ax_gather<<<(NN*64+255)/256, 256, 0, stream>>>(xTb, row_ptr, csr, AXb);
    w1sum_kernel<<<32, 256, 0, stream>>>(W1, W1s);

    const int grid = 625*4;   // 16 rows/block, 4 batches
    for (int t=0; t<TT; ++t) {
        layer_kernel<1><<<grid, 512, 0, stream>>>(h,  x, AXb, W0,  b0, row_ptr, csr, h1, t);
        layer_kernel<0><<<grid, 512, 0, stream>>>(h1, nullptr, nullptr, W1s, b1, row_ptr, csr, h, 0);
    }
    out_kernel<<<(BB*NN*64+255)/256, 256, 0, stream>>>(h, Wp, bp, outp);
}

// Round 5
// 1076.619 us; speedup vs baseline: 4.8584x; 1.1341x over previous
//
#include <hip/hip_runtime.h>

#define BB 4
#define TT 12
#define NN 10000
#define DD 2
#define EE 320000
#define HH 64
#define NPREDD 12
#define TD 24

typedef __attribute__((ext_vector_type(8))) short bf16x8;
typedef __attribute__((ext_vector_type(4))) float f32x4;

__device__ __forceinline__ unsigned int pack2(float lo, float hi) {
    unsigned int r;
    asm("v_cvt_pk_bf16_f32 %0, %1, %2" : "=v"(r) : "v"(lo), "v"(hi));
    return r;
}

// ---------------- CSR build (keyed by dst; gather from src) ----------------
__global__ void hist_kernel(const int* __restrict__ dstv, int* __restrict__ deg) {
    int e = blockIdx.x*256 + threadIdx.x;
    if (e < EE) atomicAdd(&deg[dstv[e]], 1);
}

__global__ void scan_kernel(const int* __restrict__ deg, int* __restrict__ row_ptr,
                            int* __restrict__ cursor) {
    __shared__ int part[1024];
    int tid = threadIdx.x;
    const int CH = 10;
    int start = tid*CH;
    int s = 0;
    if (start < NN)
        for (int i=0;i<CH;i++) s += deg[start+i];
    part[tid] = s;
    __syncthreads();
    if (tid == 0) {
        int acc = 0;
        for (int i=0;i<1024;i++){ int v=part[i]; part[i]=acc; acc+=v; }
        row_ptr[NN] = acc;
    }
    __syncthreads();
    if (start < NN) {
        int acc = part[tid];
        for (int i=0;i<CH;i++){ int idx=start+i; row_ptr[idx]=acc; cursor[idx]=acc; acc+=deg[idx]; }
    }
}

__global__ void fill_kernel(const int* __restrict__ srcv, const int* __restrict__ dstv,
                            const float* __restrict__ ew, int* __restrict__ cursor,
                            int2* __restrict__ csr) {
    int e = blockIdx.x*256 + threadIdx.x;
    if (e < EE) {
        int d = dstv[e];
        int pos = atomicAdd(&cursor[d], 1);
        csr[pos] = make_int2(srcv[e], __float_as_int(ew[e]));
    }
}

// ---------------- x transpose: [B,T,N,D] -> [N][T*D][B] (batch fastest) ----------------
__global__ void transpose_x(const float* __restrict__ x, float* __restrict__ xTb) {
    int idx = blockIdx.x*256 + threadIdx.x;
    if (idx >= BB*TT*NN*DD) return;
    int d = idx & 1;
    int n = (idx >> 1) % NN;
    int t = (idx / (NN*DD)) % TT;
    int b = idx / (TT*NN*DD);
    xTb[((size_t)n*TD + (t*DD + d))*BB + b] = x[idx];
}

// ---------------- AX = A @ x_t for all t,b at once; layout [N][TD][B] ----------------
__global__ __launch_bounds__(256)
void ax_gather(const float* __restrict__ xTb, const int* __restrict__ row_ptr,
               const int2* __restrict__ csr, float* __restrict__ AXb) {
    int gw = (blockIdx.x*256 + threadIdx.x) >> 6;
    if (gw >= NN) return;
    int n = gw;
    int lane = threadIdx.x & 63;
    int half = lane >> 5;
    int c = lane & 31;
    float4 acc = {0.f,0.f,0.f,0.f};
    int e0 = row_ptr[n], e1 = row_ptr[n+1];
    for (int e = e0; e < e1; e += 4) {
        int ia = e + half;
        int ib = e + 2 + half;
        int2 ca = csr[ia];
        int2 cb = csr[ib];
        float wa = (ia < e1) ? __int_as_float(ca.y) : 0.f;
        float wb = (ib < e1) ? __int_as_float(cb.y) : 0.f;
        const float4 va = *(const float4*)(xTb + (size_t)ca.x*(TD*BB) + c*4);
        const float4 vb = *(const float4*)(xTb + (size_t)cb.x*(TD*BB) + c*4);
        acc.x = fmaf(wa, va.x, acc.x); acc.y = fmaf(wa, va.y, acc.y);
        acc.z = fmaf(wa, va.z, acc.z); acc.w = fmaf(wa, va.w, acc.w);
        acc.x = fmaf(wb, vb.x, acc.x); acc.y = fmaf(wb, vb.y, acc.y);
        acc.z = fmaf(wb, vb.z, acc.z); acc.w = fmaf(wb, vb.w, acc.w);
    }
    acc.x += __shfl_xor(acc.x, 32); acc.y += __shfl_xor(acc.y, 32);
    acc.z += __shfl_xor(acc.z, 32); acc.w += __shfl_xor(acc.w, 32);
    if (lane < TD) *(float4*)(AXb + (size_t)n*(TD*BB) + lane*4) = acc;
}

// ---------------- weight fragments in MFMA B-operand order ----------------
// wf[ct][kt][lane][j] (8 bf16 = 16B per lane): value = Wrow(k)[c],
// k = kt*32 + (lane>>4)*8 + j, c = ct*16 + (lane&15).
// L0 rows: k<64 -> W0[0][2+k], k<128 -> W0[1][2+(k-64)], 128..131 -> W0[0][0],W0[0][1],W0[1][0],W0[1][1], else 0
// L1 rows: k<64 -> W1[0][k]+W1[0][64+k], k<128 -> W1[1][k-64]+W1[1][k], else 0
__global__ void prep_wfrag(const float* __restrict__ W0, const float* __restrict__ W1,
                           unsigned short* __restrict__ wf0, unsigned short* __restrict__ wf1) {
    int tid = blockIdx.x*256 + threadIdx.x;
    if (tid >= 2560) return;
    int layer = tid / 1280;
    int r = tid % 1280;
    int lane = r & 63;
    int ctkt = r >> 6;
    int ct = ctkt / 5, kt = ctkt % 5;
    int c = ct*16 + (lane & 15);
    int k0 = kt*32 + (lane >> 4)*8;
    unsigned short* dst = (layer ? wf1 : wf0) + r*8;
    for (int j=0;j<8;j++) {
        int k = k0 + j;
        float w = 0.f;
        if (layer == 0) {
            if (k < 64)        w = W0[(2+k)*64 + c];
            else if (k < 128)  w = W0[4224 + (2+(k-64))*64 + c];
            else if (k == 128) w = W0[c];
            else if (k == 129) w = W0[64 + c];
            else if (k == 130) w = W0[4224 + c];
            else if (k == 131) w = W0[4224 + 64 + c];
        } else {
            if (k < 64)        w = W1[k*64 + c] + W1[(k+64)*64 + c];
            else if (k < 128)  w = W1[8192 + (k-64)*64 + c] + W1[8192 + k*64 + c];
        }
        unsigned int u = __float_as_uint(w);
        unsigned int rnd = (u + 0x7fffu + ((u >> 16) & 1u)) >> 16;   // RNE
        dst[j] = (unsigned short)rnd;
    }
}

// ---------------- fused layer: f32 gather -> bf16 LDS stage -> MFMA GEMM ----------------
// 512 threads = 8 waves; 32 rows/block (4 rows/wave gather; 8 C-tiles of 16x16).
template<int L0>
__global__ __launch_bounds__(512)
void layer_kernel(const float* __restrict__ h_in,
                  const float* __restrict__ x,
                  const float* __restrict__ AXb,
                  const unsigned short* __restrict__ wf,
                  const float* __restrict__ bias,
                  const int* __restrict__ row_ptr,
                  const int2* __restrict__ csr,
                  float* __restrict__ h_out,
                  int t)
{
    __shared__ unsigned short sA[32*168];   // [row][k], k: 0..63 h, 64..127 Ah, 128..131 extras, 132..159 zeros

    int tid = threadIdx.x;
    int wave = tid >> 6, lane = tid & 63;
    int g = lane >> 4, c = lane & 15;
    int b = blockIdx.x & 3;          // batch -> XCD pairing keeps gather set in L2
    int chunk = blockIdx.x >> 2;     // 0..312
    const float* hb = h_in + (size_t)b*NN*HH;
    float* ho = h_out + (size_t)b*NN*HH;

    // preload this wave's B fragments (col-tile ct) and bias
    int ct = wave & 3, rt = wave >> 2;
    const bf16x8* wfv = (const bf16x8*)wf;
    bf16x8 bfr[5];
    #pragma unroll
    for (int kt=0; kt<5; ++kt) bfr[kt] = wfv[(ct*5+kt)*64 + lane];
    float bv = bias[ct*16 + c];

    int n0 = chunk*32 + wave*4;
    #pragma unroll
    for (int i=0;i<4;i++) {
        int n = n0 + i;
        int nn = n < NN ? n : NN-1;
        float4 hv = *(const float4*)(hb + (size_t)nn*HH + c*4);
        float4 acc = {0.f,0.f,0.f,0.f};
        int e0 = row_ptr[nn], e1 = row_ptr[nn+1];
        for (int e = e0; e < e1; e += 8) {
            int i0 = e + 2*g;
            int2 cw0 = csr[i0];                      // pad-safe
            int2 cw1 = csr[i0+1];
            float w0 = (i0   < e1) ? __int_as_float(cw0.y) : 0.f;
            float w1 = (i0+1 < e1) ? __int_as_float(cw1.y) : 0.f;
            const float4 v0 = *(const float4*)(hb + (size_t)cw0.x*HH + c*4);
            const float4 v1 = *(const float4*)(hb + (size_t)cw1.x*HH + c*4);
            acc.x = fmaf(w0, v0.x, acc.x); acc.y = fmaf(w0, v0.y, acc.y);
            acc.z = fmaf(w0, v0.z, acc.z); acc.w = fmaf(w0, v0.w, acc.w);
            acc.x = fmaf(w1, v1.x, acc.x); acc.y = fmaf(w1, v1.y, acc.y);
            acc.z = fmaf(w1, v1.z, acc.z); acc.w = fmaf(w1, v1.w, acc.w);
        }
        acc.x += __shfl_xor(acc.x, 16); acc.y += __shfl_xor(acc.y, 16);
        acc.z += __shfl_xor(acc.z, 16); acc.w += __shfl_xor(acc.w, 16);
        acc.x += __shfl_xor(acc.x, 32); acc.y += __shfl_xor(acc.y, 32);
        acc.z += __shfl_xor(acc.z, 32); acc.w += __shfl_xor(acc.w, 32);

        int rowL = wave*4 + i;
        if (g == 0) {
            uint2 p; p.x = pack2(hv.x, hv.y); p.y = pack2(hv.z, hv.w);
            *(uint2*)&sA[rowL*168 + c*4] = p;
        } else if (g == 1) {
            uint2 p; p.x = pack2(acc.x, acc.y); p.y = pack2(acc.z, acc.w);
            *(uint2*)&sA[rowL*168 + 64 + c*4] = p;
        } else if (g == 2 && c == 0) {
            uint2 p;
            if (L0) {
                const float2 xv = *(const float2*)(x + (((size_t)b*TT + t)*NN + nn)*DD);
                float ax0 = AXb[(size_t)nn*(TD*BB) + (2*t)*BB + b];
                float ax1 = AXb[(size_t)nn*(TD*BB) + (2*t+1)*BB + b];
                p.x = pack2(xv.x, xv.y); p.y = pack2(ax0, ax1);
            } else {
                p.x = 0u; p.y = 0u;
            }
            *(uint2*)&sA[rowL*168 + 128] = p;
        } else if (g == 3 && c < 7) {
            *(uint2*)&sA[rowL*168 + 132 + c*4] = make_uint2(0u, 0u);
        }
    }
    __syncthreads();

    // MFMA: C-tile (rt, ct), A row = lane&15, k = (lane>>4)*8 + j
    f32x4 dacc = {0.f,0.f,0.f,0.f};
    #pragma unroll
    for (int kt=0; kt<5; ++kt) {
        bf16x8 a = *(const bf16x8*)&sA[(rt*16 + c)*168 + kt*32 + g*8];
        dacc = __builtin_amdgcn_mfma_f32_16x16x32_bf16(a, bfr[kt], dacc, 0, 0, 0);
    }
    #pragma unroll
    for (int i2=0;i2<4;i2++) {
        int r = rt*16 + g*4 + i2;            // C/D: row=(lane>>4)*4+reg, col=lane&15
        int n = chunk*32 + r;
        if (n < NN) ho[(size_t)n*HH + ct*16 + c] = fmaxf(dacc[i2] + bv, 0.f);
    }
}

// ---------------- output ----------------
__global__ void out_kernel(const float* __restrict__ h, const float* __restrict__ Wp,
                           const float* __restrict__ bp, float* __restrict__ outp) {
    int g = blockIdx.x*256 + threadIdx.x;
    int wave = g >> 6, lane = g & 63;
    if (wave >= BB*NN) return;
    int b = wave / NN, n = wave - b*NN;
    float v = h[(size_t)wave*HH + lane] * Wp[lane];
    for (int off=32; off; off>>=1) v += __shfl_down(v, off);
    v = __shfl(v, 0) + bp[0];
    if (lane < NPREDD) outp[((size_t)b*NPREDD + lane)*NN + n] = v;
}

extern "C" void kernel_launch(void* const* d_in, const int* in_sizes, int n_in,
                              void* d_out, int out_size, void* d_ws, size_t ws_size,
                              hipStream_t stream) {
    const float* x   = (const float*)d_in[0];
    const int*   ei  = (const int*)d_in[1];
    const float* ew  = (const float*)d_in[2];
    const float* W0  = (const float*)d_in[3];
    const float* b0  = (const float*)d_in[4];
    const float* W1  = (const float*)d_in[5];
    const float* b1  = (const float*)d_in[6];
    const float* Wp  = (const float*)d_in[7];
    const float* bp  = (const float*)d_in[8];
    float* outp = (float*)d_out;

    char* ws = (char*)d_ws;
    size_t off = 0;
    auto alloc = [&](size_t bytes) { void* p = ws + off; off = (off + bytes + 255) & ~(size_t)255; return p; };
    float* h    = (float*)alloc((size_t)BB*NN*HH*4);
    float* h1   = (float*)alloc((size_t)BB*NN*HH*4);
    float* xTb  = (float*)alloc(((size_t)NN*TD*BB + 64)*4);
    float* AXb  = (float*)alloc((size_t)NN*TD*BB*4);
    unsigned short* wf0 = (unsigned short*)alloc(1280*8*2);
    unsigned short* wf1 = (unsigned short*)alloc(1280*8*2);
    int2*  csr  = (int2*)alloc(((size_t)EE + 16)*8);
    int* row_ptr= (int*)alloc((NN+1)*4);
    int* deg    = (int*)alloc(NN*4);
    int* cursor = (int*)alloc(NN*4);

    const int* srcv = ei;
    const int* dstv = ei + EE;

    hipMemsetAsync(deg, 0, NN*4, stream);
    hipMemsetAsync(h, 0, (size_t)BB*NN*HH*4, stream);
    hipMemsetAsync(csr + EE, 0, 16*8, stream);

    hist_kernel<<<(EE+255)/256, 256, 0, stream>>>(dstv, deg);
    scan_kernel<<<1, 1024, 0, stream>>>(deg, row_ptr, cursor);
    fill_kernel<<<(EE+255)/256, 256, 0, stream>>>(srcv, dstv, ew, cursor, csr);
    transpose_x<<<(BB*TT*NN*DD+255)/256, 256, 0, stream>>>(x, xTb);
    ax_gather<<<(NN*64+255)/256, 256, 0, stream>>>(xTb, row_ptr, csr, AXb);
    prep_wfrag<<<10, 256, 0, stream>>>(W0, W1, wf0, wf1);

    const int grid = 313*4;   // 32 rows/block, 4 batches
    for (int t=0; t<TT; ++t) {
        layer_kernel<1><<<grid, 512, 0, stream>>>(h,  x, AXb, wf0, b0, row_ptr, csr, h1, t);
        layer_kernel<0><<<grid, 512, 0, stream>>>(h1, nullptr, nullptr, wf1, b1, row_ptr, csr, h, 0);
    }
    out_kernel<<<(BB*NN*64+255)/256, 256, 0, stream>>>(h, Wp, bp, outp);
}

// Round 6
// 1061.767 us; speedup vs baseline: 4.9263x; 1.0140x over previous
//
#include <hip/hip_runtime.h>

#define BB 4
#define TT 12
#define NN 10000
#define DD 2
#define EE 320000
#define HH 64
#define NPREDD 12
#define TD 24

typedef __attribute__((ext_vector_type(8))) short bf16x8;
typedef __attribute__((ext_vector_type(4))) float f32x4;
typedef unsigned short u16;

__device__ __forceinline__ unsigned int pack2(float lo, float hi) {
    unsigned int r;
    asm("v_cvt_pk_bf16_f32 %0, %1, %2" : "=v"(r) : "v"(lo), "v"(hi));
    return r;
}
__device__ __forceinline__ float b2f(u16 u) {
    return __uint_as_float(((unsigned)u) << 16);
}

// ---------------- CSR build (keyed by dst; gather from src) ----------------
__global__ void hist_kernel(const int* __restrict__ dstv, int* __restrict__ deg) {
    int e = blockIdx.x*256 + threadIdx.x;
    if (e < EE) atomicAdd(&deg[dstv[e]], 1);
}

__global__ void scan_kernel(const int* __restrict__ deg, int* __restrict__ row_ptr,
                            int* __restrict__ cursor) {
    __shared__ int part[1024];
    int tid = threadIdx.x;
    const int CH = 10;
    int start = tid*CH;
    int s = 0;
    if (start < NN)
        for (int i=0;i<CH;i++) s += deg[start+i];
    part[tid] = s;
    __syncthreads();
    if (tid == 0) {
        int acc = 0;
        for (int i=0;i<1024;i++){ int v=part[i]; part[i]=acc; acc+=v; }
        row_ptr[NN] = acc;
    }
    __syncthreads();
    if (start < NN) {
        int acc = part[tid];
        for (int i=0;i<CH;i++){ int idx=start+i; row_ptr[idx]=acc; cursor[idx]=acc; acc+=deg[idx]; }
    }
}

__global__ void fill_kernel(const int* __restrict__ srcv, const int* __restrict__ dstv,
                            const float* __restrict__ ew, int* __restrict__ cursor,
                            int2* __restrict__ csr) {
    int e = blockIdx.x*256 + threadIdx.x;
    if (e < EE) {
        int d = dstv[e];
        int pos = atomicAdd(&cursor[d], 1);
        csr[pos] = make_int2(srcv[e], __float_as_int(ew[e]));
    }
}

// ---------------- x transpose: [B,T,N,D] -> [N][T*D][B] (batch fastest) ----------------
__global__ void transpose_x(const float* __restrict__ x, float* __restrict__ xTb) {
    int idx = blockIdx.x*256 + threadIdx.x;
    if (idx >= BB*TT*NN*DD) return;
    int d = idx & 1;
    int n = (idx >> 1) % NN;
    int t = (idx / (NN*DD)) % TT;
    int b = idx / (TT*NN*DD);
    xTb[((size_t)n*TD + (t*DD + d))*BB + b] = x[idx];
}

// ---------------- AX = A @ x_t for all t,b at once; layout [N][TD][B] ----------------
__global__ __launch_bounds__(256)
void ax_gather(const float* __restrict__ xTb, const int* __restrict__ row_ptr,
               const int2* __restrict__ csr, float* __restrict__ AXb) {
    int gw = (blockIdx.x*256 + threadIdx.x) >> 6;
    if (gw >= NN) return;
    int n = gw;
    int lane = threadIdx.x & 63;
    int half = lane >> 5;
    int c = lane & 31;
    float4 acc = {0.f,0.f,0.f,0.f};
    int e0 = row_ptr[n], e1 = row_ptr[n+1];
    for (int e = e0; e < e1; e += 4) {
        int ia = e + half;
        int ib = e + 2 + half;
        int2 ca = csr[ia];
        int2 cb = csr[ib];
        float wa = (ia < e1) ? __int_as_float(ca.y) : 0.f;
        float wb = (ib < e1) ? __int_as_float(cb.y) : 0.f;
        const float4 va = *(const float4*)(xTb + (size_t)ca.x*(TD*BB) + c*4);
        const float4 vb = *(const float4*)(xTb + (size_t)cb.x*(TD*BB) + c*4);
        acc.x = fmaf(wa, va.x, acc.x); acc.y = fmaf(wa, va.y, acc.y);
        acc.z = fmaf(wa, va.z, acc.z); acc.w = fmaf(wa, va.w, acc.w);
        acc.x = fmaf(wb, vb.x, acc.x); acc.y = fmaf(wb, vb.y, acc.y);
        acc.z = fmaf(wb, vb.z, acc.z); acc.w = fmaf(wb, vb.w, acc.w);
    }
    acc.x += __shfl_xor(acc.x, 32); acc.y += __shfl_xor(acc.y, 32);
    acc.z += __shfl_xor(acc.z, 32); acc.w += __shfl_xor(acc.w, 32);
    if (lane < TD) *(float4*)(AXb + (size_t)n*(TD*BB) + lane*4) = acc;
}

// ---------------- weight fragments in MFMA B-operand order ----------------
__global__ void prep_wfrag(const float* __restrict__ W0, const float* __restrict__ W1,
                           unsigned short* __restrict__ wf0, unsigned short* __restrict__ wf1) {
    int tid = blockIdx.x*256 + threadIdx.x;
    if (tid >= 2560) return;
    int layer = tid / 1280;
    int r = tid % 1280;
    int lane = r & 63;
    int ctkt = r >> 6;
    int ct = ctkt / 5, kt = ctkt % 5;
    int c = ct*16 + (lane & 15);
    int k0 = kt*32 + (lane >> 4)*8;
    unsigned short* dst = (layer ? wf1 : wf0) + r*8;
    for (int j=0;j<8;j++) {
        int k = k0 + j;
        float w = 0.f;
        if (layer == 0) {
            if (k < 64)        w = W0[(2+k)*64 + c];
            else if (k < 128)  w = W0[4224 + (2+(k-64))*64 + c];
            else if (k == 128) w = W0[c];
            else if (k == 129) w = W0[64 + c];
            else if (k == 130) w = W0[4224 + c];
            else if (k == 131) w = W0[4224 + 64 + c];
        } else {
            if (k < 64)        w = W1[k*64 + c] + W1[(k+64)*64 + c];
            else if (k < 128)  w = W1[8192 + (k-64)*64 + c] + W1[8192 + k*64 + c];
        }
        unsigned int u = __float_as_uint(w);
        unsigned int rnd = (u + 0x7fffu + ((u >> 16) & 1u)) >> 16;   // RNE
        dst[j] = (unsigned short)rnd;
    }
}

// ---------------- fused layer: bf16 gather -> bf16 LDS stage -> MFMA GEMM ----------------
// h state is bf16 [B][N][64] (128 B/row). 512 threads = 8 waves; 32 rows/block.
template<int L0>
__global__ __launch_bounds__(512)
void layer_kernel(const u16* __restrict__ h_in,
                  const float* __restrict__ x,
                  const float* __restrict__ AXb,
                  const unsigned short* __restrict__ wf,
                  const float* __restrict__ bias,
                  const int* __restrict__ row_ptr,
                  const int2* __restrict__ csr,
                  u16* __restrict__ h_out,
                  int t)
{
    __shared__ unsigned short sA[32*168];   // [row][k] bf16; k: 0..63 h, 64..127 Ah, 128..131 extras, 132..159 zeros

    int tid = threadIdx.x;
    int wave = tid >> 6, lane = tid & 63;
    int g = lane >> 4, c = lane & 15;
    int b = blockIdx.x & 3;          // batch pinned per XCD: h(1.28MB)+csr(2.56MB) fits 4MB L2
    int chunk = blockIdx.x >> 2;     // 0..312
    const u16* hb = h_in + (size_t)b*NN*HH;
    u16* ho = h_out + (size_t)b*NN*HH;

    int ct = wave & 3, rt = wave >> 2;
    const bf16x8* wfv = (const bf16x8*)wf;
    bf16x8 bfr[5];
    #pragma unroll
    for (int kt=0; kt<5; ++kt) bfr[kt] = wfv[(ct*5+kt)*64 + lane];
    float bv = bias[ct*16 + c];

    int n0 = chunk*32 + wave*4;
    #pragma unroll
    for (int i=0;i<4;i++) {
        int n = n0 + i;
        int nn = n < NN ? n : NN-1;
        ushort4 hv = *(const ushort4*)(hb + (size_t)nn*HH + c*4);   // direct term, raw bf16 bits
        float4 acc = {0.f,0.f,0.f,0.f};
        int e0 = row_ptr[nn], e1 = row_ptr[nn+1];
        for (int e = e0; e < e1; e += 8) {
            int i0 = e + 2*g;                        // this group's 2 edges
            int2 cw0 = csr[i0];                      // pad-safe (16 zeroed tail entries)
            int2 cw1 = csr[i0+1];
            float w0 = (i0   < e1) ? __int_as_float(cw0.y) : 0.f;
            float w1 = (i0+1 < e1) ? __int_as_float(cw1.y) : 0.f;
            ushort4 v0 = *(const ushort4*)(hb + (size_t)cw0.x*HH + c*4);   // 8B = 4 bf16
            ushort4 v1 = *(const ushort4*)(hb + (size_t)cw1.x*HH + c*4);
            acc.x = fmaf(w0, b2f(v0.x), acc.x); acc.y = fmaf(w0, b2f(v0.y), acc.y);
            acc.z = fmaf(w0, b2f(v0.z), acc.z); acc.w = fmaf(w0, b2f(v0.w), acc.w);
            acc.x = fmaf(w1, b2f(v1.x), acc.x); acc.y = fmaf(w1, b2f(v1.y), acc.y);
            acc.z = fmaf(w1, b2f(v1.z), acc.z); acc.w = fmaf(w1, b2f(v1.w), acc.w);
        }
        acc.x += __shfl_xor(acc.x, 16); acc.y += __shfl_xor(acc.y, 16);
        acc.z += __shfl_xor(acc.z, 16); acc.w += __shfl_xor(acc.w, 16);
        acc.x += __shfl_xor(acc.x, 32); acc.y += __shfl_xor(acc.y, 32);
        acc.z += __shfl_xor(acc.z, 32); acc.w += __shfl_xor(acc.w, 32);

        int rowL = wave*4 + i;
        if (g == 0) {
            *(ushort4*)&sA[rowL*168 + c*4] = hv;
        } else if (g == 1) {
            uint2 p; p.x = pack2(acc.x, acc.y); p.y = pack2(acc.z, acc.w);
            *(uint2*)&sA[rowL*168 + 64 + c*4] = p;
        } else if (g == 2 && c == 0) {
            uint2 p;
            if (L0) {
                const float2 xv = *(const float2*)(x + (((size_t)b*TT + t)*NN + nn)*DD);
                float ax0 = AXb[(size_t)nn*(TD*BB) + (2*t)*BB + b];
                float ax1 = AXb[(size_t)nn*(TD*BB) + (2*t+1)*BB + b];
                p.x = pack2(xv.x, xv.y); p.y = pack2(ax0, ax1);
            } else {
                p.x = 0u; p.y = 0u;
            }
            *(uint2*)&sA[rowL*168 + 128] = p;
        } else if (g == 3 && c < 7) {
            *(uint2*)&sA[rowL*168 + 132 + c*4] = make_uint2(0u, 0u);
        }
    }
    __syncthreads();

    // MFMA: C-tile (rt, ct); A row = lane&15, k = (lane>>4)*8 + j
    f32x4 dacc = {0.f,0.f,0.f,0.f};
    #pragma unroll
    for (int kt=0; kt<5; ++kt) {
        bf16x8 a = *(const bf16x8*)&sA[(rt*16 + c)*168 + kt*32 + g*8];
        dacc = __builtin_amdgcn_mfma_f32_16x16x32_bf16(a, bfr[kt], dacc, 0, 0, 0);
    }
    #pragma unroll
    for (int i2=0;i2<4;i2++) {
        int r = rt*16 + g*4 + i2;            // C/D: row=(lane>>4)*4+reg, col=lane&15
        int n = chunk*32 + r;
        if (n < NN) {
            float v = fmaxf(dacc[i2] + bv, 0.f);
            unsigned p = pack2(v, v);
            ho[(size_t)n*HH + ct*16 + c] = (u16)p;
        }
    }
}

// ---------------- output ----------------
__global__ void out_kernel(const u16* __restrict__ h, const float* __restrict__ Wp,
                           const float* __restrict__ bp, float* __restrict__ outp) {
    int g = blockIdx.x*256 + threadIdx.x;
    int wave = g >> 6, lane = g & 63;
    if (wave >= BB*NN) return;
    int b = wave / NN, n = wave - b*NN;
    float v = b2f(h[(size_t)wave*HH + lane]) * Wp[lane];
    for (int off=32; off; off>>=1) v += __shfl_down(v, off);
    v = __shfl(v, 0) + bp[0];
    if (lane < NPREDD) outp[((size_t)b*NPREDD + lane)*NN + n] = v;
}

extern "C" void kernel_launch(void* const* d_in, const int* in_sizes, int n_in,
                              void* d_out, int out_size, void* d_ws, size_t ws_size,
                              hipStream_t stream) {
    const float* x   = (const float*)d_in[0];
    const int*   ei  = (const int*)d_in[1];
    const float* ew  = (const float*)d_in[2];
    const float* W0  = (const float*)d_in[3];
    const float* b0  = (const float*)d_in[4];
    const float* W1  = (const float*)d_in[5];
    const float* b1  = (const float*)d_in[6];
    const float* Wp  = (const float*)d_in[7];
    const float* bp  = (const float*)d_in[8];
    float* outp = (float*)d_out;

    char* ws = (char*)d_ws;
    size_t off = 0;
    auto alloc = [&](size_t bytes) { void* p = ws + off; off = (off + bytes + 255) & ~(size_t)255; return p; };
    u16* h      = (u16*)alloc((size_t)BB*NN*HH*2);
    u16* h1     = (u16*)alloc((size_t)BB*NN*HH*2);
    float* xTb  = (float*)alloc(((size_t)NN*TD*BB + 64)*4);
    float* AXb  = (float*)alloc((size_t)NN*TD*BB*4);
    unsigned short* wf0 = (unsigned short*)alloc(1280*8*2);
    unsigned short* wf1 = (unsigned short*)alloc(1280*8*2);
    int2*  csr  = (int2*)alloc(((size_t)EE + 16)*8);
    int* row_ptr= (int*)alloc((NN+1)*4);
    int* deg    = (int*)alloc(NN*4);
    int* cursor = (int*)alloc(NN*4);

    const int* srcv = ei;
    const int* dstv = ei + EE;

    hipMemsetAsync(deg, 0, NN*4, stream);
    hipMemsetAsync(h, 0, (size_t)BB*NN*HH*2, stream);
    hipMemsetAsync(csr + EE, 0, 16*8, stream);

    hist_kernel<<<(EE+255)/256, 256, 0, stream>>>(dstv, deg);
    scan_kernel<<<1, 1024, 0, stream>>>(deg, row_ptr, cursor);
    fill_kernel<<<(EE+255)/256, 256, 0, stream>>>(srcv, dstv, ew, cursor, csr);
    transpose_x<<<(BB*TT*NN*DD+255)/256, 256, 0, stream>>>(x, xTb);
    ax_gather<<<(NN*64+255)/256, 256, 0, stream>>>(xTb, row_ptr, csr, AXb);
    prep_wfrag<<<10, 256, 0, stream>>>(W0, W1, wf0, wf1);

    const int grid = 313*4;   // 32 rows/block, 4 batches
    for (int t=0; t<TT; ++t) {
        layer_kernel<1><<<grid, 512, 0, stream>>>(h,  x, AXb, wf0, b0, row_ptr, csr, h1, t);
        layer_kernel<0><<<grid, 512, 0, stream>>>(h1, nullptr, nullptr, wf1, b1, row_ptr, csr, h, 0);
    }
    out_kernel<<<(BB*NN*64+255)/256, 256, 0, stream>>>(h, Wp, bp, outp);
}

// Round 7
// 819.671 us; speedup vs baseline: 6.3814x; 1.2954x over previous
//
#include <hip/hip_runtime.h>

#define BB 4
#define TT 12
#define NN 10000
#define DD 2
#define EE 320000
#define HH 64
#define NPREDD 12
#define TD 24
#define CAP 2048

typedef __attribute__((ext_vector_type(8))) short bf16x8;
typedef __attribute__((ext_vector_type(4))) float f32x4;
typedef unsigned short u16;

__device__ __forceinline__ unsigned int pack2(float lo, float hi) {
    unsigned int r;
    asm("v_cvt_pk_bf16_f32 %0, %1, %2" : "=v"(r) : "v"(lo), "v"(hi));
    return r;
}
__device__ __forceinline__ float b2f(u16 u) {
    return __uint_as_float(((unsigned)u) << 16);
}

// ---------------- CSR build (keyed by dst; gather from src) ----------------
__global__ void hist_kernel(const int* __restrict__ dstv, int* __restrict__ deg) {
    int e = blockIdx.x*256 + threadIdx.x;
    if (e < EE) atomicAdd(&deg[dstv[e]], 1);
}

__global__ void scan_kernel(const int* __restrict__ deg, int* __restrict__ row_ptr,
                            int* __restrict__ cursor) {
    __shared__ int part[1024];
    int tid = threadIdx.x;
    const int CH = 10;
    int start = tid*CH;
    int s = 0;
    if (start < NN)
        for (int i=0;i<CH;i++) s += deg[start+i];
    part[tid] = s;
    __syncthreads();
    if (tid == 0) {
        int acc = 0;
        for (int i=0;i<1024;i++){ int v=part[i]; part[i]=acc; acc+=v; }
        row_ptr[NN] = acc;
    }
    __syncthreads();
    if (start < NN) {
        int acc = part[tid];
        for (int i=0;i<CH;i++){ int idx=start+i; row_ptr[idx]=acc; cursor[idx]=acc; acc+=deg[idx]; }
    }
}

__global__ void fill_kernel(const int* __restrict__ srcv, const int* __restrict__ dstv,
                            const float* __restrict__ ew, int* __restrict__ cursor,
                            int2* __restrict__ csr) {
    int e = blockIdx.x*256 + threadIdx.x;
    if (e < EE) {
        int d = dstv[e];
        int pos = atomicAdd(&cursor[d], 1);
        csr[pos] = make_int2(srcv[e], __float_as_int(ew[e]));
    }
}

// ---------------- x transpose: [B,T,N,D] -> [N][T*D][B] (batch fastest) ----------------
__global__ void transpose_x(const float* __restrict__ x, float* __restrict__ xTb) {
    int idx = blockIdx.x*256 + threadIdx.x;
    if (idx >= BB*TT*NN*DD) return;
    int d = idx & 1;
    int n = (idx >> 1) % NN;
    int t = (idx / (NN*DD)) % TT;
    int b = idx / (TT*NN*DD);
    xTb[((size_t)n*TD + (t*DD + d))*BB + b] = x[idx];
}

// ---------------- AX = A @ x_t for all t,b at once; layout [N][TD][B] ----------------
__global__ __launch_bounds__(256)
void ax_gather(const float* __restrict__ xTb, const int* __restrict__ row_ptr,
               const int2* __restrict__ csr, float* __restrict__ AXb) {
    int gw = (blockIdx.x*256 + threadIdx.x) >> 6;
    if (gw >= NN) return;
    int n = gw;
    int lane = threadIdx.x & 63;
    int half = lane >> 5;
    int c = lane & 31;
    float4 acc = {0.f,0.f,0.f,0.f};
    int e0 = row_ptr[n], e1 = row_ptr[n+1];
    for (int e = e0; e < e1; e += 8) {         // 4 independent edge pairs in flight
        int ia = e + half, ib = e + 2 + half, ic = e + 4 + half, id = e + 6 + half;
        int2 ca = csr[ia]; int2 cb = csr[ib]; int2 cc = csr[ic]; int2 cd = csr[id];
        float wa = (ia < e1) ? __int_as_float(ca.y) : 0.f;
        float wb = (ib < e1) ? __int_as_float(cb.y) : 0.f;
        float wc = (ic < e1) ? __int_as_float(cc.y) : 0.f;
        float wd = (id < e1) ? __int_as_float(cd.y) : 0.f;
        const float4 va = *(const float4*)(xTb + (size_t)ca.x*(TD*BB) + c*4);
        const float4 vb = *(const float4*)(xTb + (size_t)cb.x*(TD*BB) + c*4);
        const float4 vc = *(const float4*)(xTb + (size_t)cc.x*(TD*BB) + c*4);
        const float4 vd = *(const float4*)(xTb + (size_t)cd.x*(TD*BB) + c*4);
        acc.x = fmaf(wa, va.x, acc.x); acc.y = fmaf(wa, va.y, acc.y);
        acc.z = fmaf(wa, va.z, acc.z); acc.w = fmaf(wa, va.w, acc.w);
        acc.x = fmaf(wb, vb.x, acc.x); acc.y = fmaf(wb, vb.y, acc.y);
        acc.z = fmaf(wb, vb.z, acc.z); acc.w = fmaf(wb, vb.w, acc.w);
        acc.x = fmaf(wc, vc.x, acc.x); acc.y = fmaf(wc, vc.y, acc.y);
        acc.z = fmaf(wc, vc.z, acc.z); acc.w = fmaf(wc, vc.w, acc.w);
        acc.x = fmaf(wd, vd.x, acc.x); acc.y = fmaf(wd, vd.y, acc.y);
        acc.z = fmaf(wd, vd.z, acc.z); acc.w = fmaf(wd, vd.w, acc.w);
    }
    acc.x += __shfl_xor(acc.x, 32); acc.y += __shfl_xor(acc.y, 32);
    acc.z += __shfl_xor(acc.z, 32); acc.w += __shfl_xor(acc.w, 32);
    if (lane < TD) *(float4*)(AXb + (size_t)n*(TD*BB) + lane*4) = acc;
}

// ---------------- weight fragments in MFMA B-operand order ----------------
__global__ void prep_wfrag(const float* __restrict__ W0, const float* __restrict__ W1,
                           unsigned short* __restrict__ wf0, unsigned short* __restrict__ wf1) {
    int tid = blockIdx.x*256 + threadIdx.x;
    if (tid >= 2560) return;
    int layer = tid / 1280;
    int r = tid % 1280;
    int lane = r & 63;
    int ctkt = r >> 6;
    int ct = ctkt / 5, kt = ctkt % 5;
    int c = ct*16 + (lane & 15);
    int k0 = kt*32 + (lane >> 4)*8;
    unsigned short* dst = (layer ? wf1 : wf0) + r*8;
    for (int j=0;j<8;j++) {
        int k = k0 + j;
        float w = 0.f;
        if (layer == 0) {
            if (k < 64)        w = W0[(2+k)*64 + c];
            else if (k < 128)  w = W0[4224 + (2+(k-64))*64 + c];
            else if (k == 128) w = W0[c];
            else if (k == 129) w = W0[64 + c];
            else if (k == 130) w = W0[4224 + c];
            else if (k == 131) w = W0[4224 + 64 + c];
        } else {
            if (k < 64)        w = W1[k*64 + c] + W1[(k+64)*64 + c];
            else if (k < 128)  w = W1[8192 + (k-64)*64 + c] + W1[8192 + k*64 + c];
        }
        unsigned int u = __float_as_uint(w);
        unsigned int rnd = (u + 0x7fffu + ((u >> 16) & 1u)) >> 16;   // RNE
        dst[j] = (unsigned short)rnd;
    }
}

// ---------------- fused layer: LDS-staged indices -> fused bf16 gather -> MFMA ----------------
// 512 threads = 8 waves; 32 rows/block; block's csr segment staged in LDS.
template<int L0>
__global__ __launch_bounds__(512)
void layer_kernel(const u16* __restrict__ h_in,
                  const float* __restrict__ x,
                  const float* __restrict__ AXb,
                  const unsigned short* __restrict__ wf,
                  const float* __restrict__ bias,
                  const int* __restrict__ row_ptr,
                  const int2* __restrict__ csr,
                  u16* __restrict__ h_out,
                  int t)
{
    __shared__ int2 sIdx[CAP];              // 16 KB: block's contiguous csr segment
    __shared__ unsigned short sA[32*168];   // 10.5 KB: bf16 MFMA A tile

    int tid = threadIdx.x;
    int wave = tid >> 6, lane = tid & 63;
    int g = lane >> 4, c = lane & 15;
    int b = blockIdx.x & 3;          // batch pinned: h(1.28MB)+csr(2.56MB) fits XCD L2
    int chunk = blockIdx.x >> 2;     // 0..312
    const u16* hb = h_in + (size_t)b*NN*HH;
    u16* ho = h_out + (size_t)b*NN*HH;

    int n0 = chunk*32;
    int nclamp = (n0 + 32 <= NN) ? n0 + 32 : NN;
    int estart = row_ptr[n0];
    int eend   = row_ptr[nclamp];
    int cnt = eend - estart; if (cnt > CAP) cnt = CAP;

    // stage csr segment (coalesced; zero-fill rest so any masked index is a valid node)
    #pragma unroll
    for (int k=0;k<CAP/512;k++) {
        int i = tid + k*512;
        int2 v = make_int2(0, 0);
        if (i < cnt) v = csr[estart + i];
        sIdx[i] = v;
    }

    // wave's B fragments + bias (independent loads, overlap staging)
    int ct = wave & 3, rt = wave >> 2;
    const bf16x8* wfv = (const bf16x8*)wf;
    bf16x8 bfr[5];
    #pragma unroll
    for (int kt=0; kt<5; ++kt) bfr[kt] = wfv[(ct*5+kt)*64 + lane];
    float bv = bias[ct*16 + c];

    // row extents (scalar) + direct-term rows (issue before barrier)
    int nw = n0 + wave*4;
    int bi[4], ei[4], tmax = 0;
    ushort4 hv[4];
    #pragma unroll
    for (int i=0;i<4;i++) {
        int nn = nw + i; nn = nn < NN ? nn : NN-1;
        bi[i] = row_ptr[nn] - estart;
        ei[i] = row_ptr[nn+1] - estart;
        int tr = (ei[i] - bi[i] + 7) >> 3;
        tmax = tr > tmax ? tr : tmax;
        hv[i] = *(const ushort4*)(hb + (size_t)nn*HH + c*4);
    }

    __syncthreads();

    float4 acc[4];
    #pragma unroll
    for (int i=0;i<4;i++) acc[i] = make_float4(0.f,0.f,0.f,0.f);

    bool slow = (ei[0] > cnt) | (ei[1] > cnt) | (ei[2] > cnt) | (ei[3] > cnt);
    if (!slow) {
        // fused 4-row gather: 8 independent 8B gathers in flight per trip
        for (int tt = 0; tt < tmax; ++tt) {
            #pragma unroll
            for (int i=0;i<4;i++) {
                int idx = bi[i] + tt*8 + 2*g;
                int2 c0 = sIdx[idx & (CAP-1)];
                int2 c1 = sIdx[(idx+1) & (CAP-1)];
                float w0 = (idx   < ei[i]) ? __int_as_float(c0.y) : 0.f;
                float w1 = (idx+1 < ei[i]) ? __int_as_float(c1.y) : 0.f;
                ushort4 v0 = *(const ushort4*)(hb + (size_t)c0.x*HH + c*4);
                ushort4 v1 = *(const ushort4*)(hb + (size_t)c1.x*HH + c*4);
                acc[i].x = fmaf(w0, b2f(v0.x), acc[i].x); acc[i].y = fmaf(w0, b2f(v0.y), acc[i].y);
                acc[i].z = fmaf(w0, b2f(v0.z), acc[i].z); acc[i].w = fmaf(w0, b2f(v0.w), acc[i].w);
                acc[i].x = fmaf(w1, b2f(v1.x), acc[i].x); acc[i].y = fmaf(w1, b2f(v1.y), acc[i].y);
                acc[i].z = fmaf(w1, b2f(v1.z), acc[i].z); acc[i].w = fmaf(w1, b2f(v1.w), acc[i].w);
            }
        }
    } else {
        // fallback: block segment > CAP (practically unreachable) — global csr path
        #pragma unroll
        for (int i=0;i<4;i++) {
            int e0g = estart + bi[i], e1g = estart + ei[i];
            for (int e = e0g; e < e1g; e += 8) {
                int i0 = e + 2*g;
                int2 cw0 = csr[i0];
                int2 cw1 = csr[i0+1];
                float w0 = (i0   < e1g) ? __int_as_float(cw0.y) : 0.f;
                float w1 = (i0+1 < e1g) ? __int_as_float(cw1.y) : 0.f;
                ushort4 v0 = *(const ushort4*)(hb + (size_t)cw0.x*HH + c*4);
                ushort4 v1 = *(const ushort4*)(hb + (size_t)cw1.x*HH + c*4);
                acc[i].x = fmaf(w0, b2f(v0.x), acc[i].x); acc[i].y = fmaf(w0, b2f(v0.y), acc[i].y);
                acc[i].z = fmaf(w0, b2f(v0.z), acc[i].z); acc[i].w = fmaf(w0, b2f(v0.w), acc[i].w);
                acc[i].x = fmaf(w1, b2f(v1.x), acc[i].x); acc[i].y = fmaf(w1, b2f(v1.y), acc[i].y);
                acc[i].z = fmaf(w1, b2f(v1.z), acc[i].z); acc[i].w = fmaf(w1, b2f(v1.w), acc[i].w);
            }
        }
    }

    #pragma unroll
    for (int i=0;i<4;i++) {
        float4 a = acc[i];
        a.x += __shfl_xor(a.x, 16); a.y += __shfl_xor(a.y, 16);
        a.z += __shfl_xor(a.z, 16); a.w += __shfl_xor(a.w, 16);
        a.x += __shfl_xor(a.x, 32); a.y += __shfl_xor(a.y, 32);
        a.z += __shfl_xor(a.z, 32); a.w += __shfl_xor(a.w, 32);

        int rowL = wave*4 + i;
        if (g == 0) {
            *(ushort4*)&sA[rowL*168 + c*4] = hv[i];
        } else if (g == 1) {
            uint2 p; p.x = pack2(a.x, a.y); p.y = pack2(a.z, a.w);
            *(uint2*)&sA[rowL*168 + 64 + c*4] = p;
        } else if (g == 2 && c == 0) {
            uint2 p;
            if (L0) {
                int nn = nw + i; nn = nn < NN ? nn : NN-1;
                const float2 xv = *(const float2*)(x + (((size_t)b*TT + t)*NN + nn)*DD);
                float ax0 = AXb[(size_t)nn*(TD*BB) + (2*t)*BB + b];
                float ax1 = AXb[(size_t)nn*(TD*BB) + (2*t+1)*BB + b];
                p.x = pack2(xv.x, xv.y); p.y = pack2(ax0, ax1);
            } else {
                p.x = 0u; p.y = 0u;
            }
            *(uint2*)&sA[rowL*168 + 128] = p;
        } else if (g == 3 && c < 7) {
            *(uint2*)&sA[rowL*168 + 132 + c*4] = make_uint2(0u, 0u);
        }
    }
    __syncthreads();

    // MFMA: C-tile (rt, ct); A row = lane&15, k = (lane>>4)*8 + j
    f32x4 dacc = {0.f,0.f,0.f,0.f};
    #pragma unroll
    for (int kt=0; kt<5; ++kt) {
        bf16x8 a = *(const bf16x8*)&sA[(rt*16 + c)*168 + kt*32 + g*8];
        dacc = __builtin_amdgcn_mfma_f32_16x16x32_bf16(a, bfr[kt], dacc, 0, 0, 0);
    }
    #pragma unroll
    for (int i2=0;i2<4;i2++) {
        int r = rt*16 + g*4 + i2;            // C/D: row=(lane>>4)*4+reg, col=lane&15
        int n = chunk*32 + r;
        if (n < NN) {
            float v = fmaxf(dacc[i2] + bv, 0.f);
            unsigned p = pack2(v, v);
            ho[(size_t)n*HH + ct*16 + c] = (u16)p;
        }
    }
}

// ---------------- output ----------------
__global__ void out_kernel(const u16* __restrict__ h, const float* __restrict__ Wp,
                           const float* __restrict__ bp, float* __restrict__ outp) {
    int g = blockIdx.x*256 + threadIdx.x;
    int wave = g >> 6, lane = g & 63;
    if (wave >= BB*NN) return;
    int b = wave / NN, n = wave - b*NN;
    float v = b2f(h[(size_t)wave*HH + lane]) * Wp[lane];
    for (int off=32; off; off>>=1) v += __shfl_down(v, off);
    v = __shfl(v, 0) + bp[0];
    if (lane < NPREDD) outp[((size_t)b*NPREDD + lane)*NN + n] = v;
}

extern "C" void kernel_launch(void* const* d_in, const int* in_sizes, int n_in,
                              void* d_out, int out_size, void* d_ws, size_t ws_size,
                              hipStream_t stream) {
    const float* x   = (const float*)d_in[0];
    const int*   ei  = (const int*)d_in[1];
    const float* ew  = (const float*)d_in[2];
    const float* W0  = (const float*)d_in[3];
    const float* b0  = (const float*)d_in[4];
    const float* W1  = (const float*)d_in[5];
    const float* b1  = (const float*)d_in[6];
    const float* Wp  = (const float*)d_in[7];
    const float* bp  = (const float*)d_in[8];
    float* outp = (float*)d_out;

    char* ws = (char*)d_ws;
    size_t off = 0;
    auto alloc = [&](size_t bytes) { void* p = ws + off; off = (off + bytes + 255) & ~(size_t)255; return p; };
    u16* h      = (u16*)alloc((size_t)BB*NN*HH*2);
    u16* h1     = (u16*)alloc((size_t)BB*NN*HH*2);
    float* xTb  = (float*)alloc(((size_t)NN*TD*BB + 64)*4);
    float* AXb  = (float*)alloc((size_t)NN*TD*BB*4);
    unsigned short* wf0 = (unsigned short*)alloc(1280*8*2);
    unsigned short* wf1 = (unsigned short*)alloc(1280*8*2);
    int2*  csr  = (int2*)alloc(((size_t)EE + 16)*8);
    int* row_ptr= (int*)alloc((NN+1)*4);
    int* deg    = (int*)alloc(NN*4);
    int* cursor = (int*)alloc(NN*4);

    const int* srcv = ei;
    const int* dstv = ei + EE;

    hipMemsetAsync(deg, 0, NN*4, stream);
    hipMemsetAsync(h, 0, (size_t)BB*NN*HH*2, stream);
    hipMemsetAsync(csr + EE, 0, 16*8, stream);

    hist_kernel<<<(EE+255)/256, 256, 0, stream>>>(dstv, deg);
    scan_kernel<<<1, 1024, 0, stream>>>(deg, row_ptr, cursor);
    fill_kernel<<<(EE+255)/256, 256, 0, stream>>>(srcv, dstv, ew, cursor, csr);
    transpose_x<<<(BB*TT*NN*DD+255)/256, 256, 0, stream>>>(x, xTb);
    ax_gather<<<(NN*64+255)/256, 256, 0, stream>>>(xTb, row_ptr, csr, AXb);
    prep_wfrag<<<10, 256, 0, stream>>>(W0, W1, wf0, wf1);

    const int grid = 313*4;   // 32 rows/block, 4 batches
    for (int t=0; t<TT; ++t) {
        layer_kernel<1><<<grid, 512, 0, stream>>>(h,  x, AXb, wf0, b0, row_ptr, csr, h1, t);
        layer_kernel<0><<<grid, 512, 0, stream>>>(h1, nullptr, nullptr, wf1, b1, row_ptr, csr, h, 0);
    }
    out_kernel<<<(BB*NN*64+255)/256, 256, 0, stream>>>(h, Wp, bp, outp);
}

// Round 8
// 698.174 us; speedup vs baseline: 7.4919x; 1.1740x over previous
//
#include <hip/hip_runtime.h>

#define BB 4
#define TT 12
#define NN 10000
#define DD 2
#define EE 320000
#define HH 64
#define NPREDD 12
#define TD 24
#define CAP 512          // per-block (8-row) csr segment capacity; mean 256, max ~340

typedef __attribute__((ext_vector_type(8))) short bf16x8;
typedef __attribute__((ext_vector_type(4))) float f32x4;
typedef unsigned short u16;

__device__ __forceinline__ unsigned int pack2(float lo, float hi) {
    unsigned int r;
    asm("v_cvt_pk_bf16_f32 %0, %1, %2" : "=v"(r) : "v"(lo), "v"(hi));
    return r;
}
__device__ __forceinline__ float b2f(u16 u) {
    return __uint_as_float(((unsigned)u) << 16);
}

// ---------------- CSR build (keyed by dst; gather from src) ----------------
__global__ void hist_kernel(const int* __restrict__ dstv, int* __restrict__ deg) {
    int e = blockIdx.x*256 + threadIdx.x;
    if (e < EE) atomicAdd(&deg[dstv[e]], 1);
}

__global__ void scan_kernel(const int* __restrict__ deg, int* __restrict__ row_ptr,
                            int* __restrict__ cursor) {
    __shared__ int part[1024];
    int tid = threadIdx.x;
    const int CH = 10;
    int start = tid*CH;
    int s = 0;
    if (start < NN)
        for (int i=0;i<CH;i++) s += deg[start+i];
    part[tid] = s;
    __syncthreads();
    if (tid == 0) {
        int acc = 0;
        for (int i=0;i<1024;i++){ int v=part[i]; part[i]=acc; acc+=v; }
        row_ptr[NN] = acc;
    }
    __syncthreads();
    if (start < NN) {
        int acc = part[tid];
        for (int i=0;i<CH;i++){ int idx=start+i; row_ptr[idx]=acc; cursor[idx]=acc; acc+=deg[idx]; }
    }
}

__global__ void fill_kernel(const int* __restrict__ srcv, const int* __restrict__ dstv,
                            const float* __restrict__ ew, int* __restrict__ cursor,
                            int2* __restrict__ csr) {
    int e = blockIdx.x*256 + threadIdx.x;
    if (e < EE) {
        int d = dstv[e];
        int pos = atomicAdd(&cursor[d], 1);
        csr[pos] = make_int2(srcv[e], __float_as_int(ew[e]));
    }
}

// ---------------- x transpose: [B,T,N,D] -> [N][T*D][B] (batch fastest) ----------------
__global__ void transpose_x(const float* __restrict__ x, float* __restrict__ xTb) {
    int idx = blockIdx.x*256 + threadIdx.x;
    if (idx >= BB*TT*NN*DD) return;
    int d = idx & 1;
    int n = (idx >> 1) % NN;
    int t = (idx / (NN*DD)) % TT;
    int b = idx / (TT*NN*DD);
    xTb[((size_t)n*TD + (t*DD + d))*BB + b] = x[idx];
}

// ---------------- AX = A @ x_t for all t,b at once; layout [N][TD][B] ----------------
__global__ __launch_bounds__(256)
void ax_gather(const float* __restrict__ xTb, const int* __restrict__ row_ptr,
               const int2* __restrict__ csr, float* __restrict__ AXb) {
    int gw = (blockIdx.x*256 + threadIdx.x) >> 6;
    if (gw >= NN) return;
    int n = gw;
    int lane = threadIdx.x & 63;
    int half = lane >> 5;
    int c = lane & 31;
    float4 acc = {0.f,0.f,0.f,0.f};
    int e0 = row_ptr[n], e1 = row_ptr[n+1];
    for (int e = e0; e < e1; e += 8) {
        int ia = e + half, ib = e + 2 + half, ic = e + 4 + half, id = e + 6 + half;
        int2 ca = csr[ia]; int2 cb = csr[ib]; int2 cc = csr[ic]; int2 cd = csr[id];
        float wa = (ia < e1) ? __int_as_float(ca.y) : 0.f;
        float wb = (ib < e1) ? __int_as_float(cb.y) : 0.f;
        float wc = (ic < e1) ? __int_as_float(cc.y) : 0.f;
        float wd = (id < e1) ? __int_as_float(cd.y) : 0.f;
        const float4 va = *(const float4*)(xTb + (size_t)ca.x*(TD*BB) + c*4);
        const float4 vb = *(const float4*)(xTb + (size_t)cb.x*(TD*BB) + c*4);
        const float4 vc = *(const float4*)(xTb + (size_t)cc.x*(TD*BB) + c*4);
        const float4 vd = *(const float4*)(xTb + (size_t)cd.x*(TD*BB) + c*4);
        acc.x = fmaf(wa, va.x, acc.x); acc.y = fmaf(wa, va.y, acc.y);
        acc.z = fmaf(wa, va.z, acc.z); acc.w = fmaf(wa, va.w, acc.w);
        acc.x = fmaf(wb, vb.x, acc.x); acc.y = fmaf(wb, vb.y, acc.y);
        acc.z = fmaf(wb, vb.z, acc.z); acc.w = fmaf(wb, vb.w, acc.w);
        acc.x = fmaf(wc, vc.x, acc.x); acc.y = fmaf(wc, vc.y, acc.y);
        acc.z = fmaf(wc, vc.z, acc.z); acc.w = fmaf(wc, vc.w, acc.w);
        acc.x = fmaf(wd, vd.x, acc.x); acc.y = fmaf(wd, vd.y, acc.y);
        acc.z = fmaf(wd, vd.z, acc.z); acc.w = fmaf(wd, vd.w, acc.w);
    }
    acc.x += __shfl_xor(acc.x, 32); acc.y += __shfl_xor(acc.y, 32);
    acc.z += __shfl_xor(acc.z, 32); acc.w += __shfl_xor(acc.w, 32);
    if (lane < TD) *(float4*)(AXb + (size_t)n*(TD*BB) + lane*4) = acc;
}

// ---------------- weight fragments in MFMA B-operand order ----------------
__global__ void prep_wfrag(const float* __restrict__ W0, const float* __restrict__ W1,
                           unsigned short* __restrict__ wf0, unsigned short* __restrict__ wf1) {
    int tid = blockIdx.x*256 + threadIdx.x;
    if (tid >= 2560) return;
    int layer = tid / 1280;
    int r = tid % 1280;
    int lane = r & 63;
    int ctkt = r >> 6;
    int ct = ctkt / 5, kt = ctkt % 5;
    int c = ct*16 + (lane & 15);
    int k0 = kt*32 + (lane >> 4)*8;
    unsigned short* dst = (layer ? wf1 : wf0) + r*8;
    for (int j=0;j<8;j++) {
        int k = k0 + j;
        float w = 0.f;
        if (layer == 0) {
            if (k < 64)        w = W0[(2+k)*64 + c];
            else if (k < 128)  w = W0[4224 + (2+(k-64))*64 + c];
            else if (k == 128) w = W0[c];
            else if (k == 129) w = W0[64 + c];
            else if (k == 130) w = W0[4224 + c];
            else if (k == 131) w = W0[4224 + 64 + c];
        } else {
            if (k < 64)        w = W1[k*64 + c] + W1[(k+64)*64 + c];
            else if (k < 128)  w = W1[8192 + (k-64)*64 + c] + W1[8192 + k*64 + c];
        }
        unsigned int u = __float_as_uint(w);
        unsigned int rnd = (u + 0x7fffu + ((u >> 16) & 1u)) >> 16;   // RNE
        dst[j] = (unsigned short)rnd;
    }
}

// ---------------- fused layer, batch-fused gather ----------------
// h layout: [N][B][64] bf16 (one node = 512 B for all 4 batches).
// 512 threads = 8 waves; 8 nodes/block (wave w owns node n0+w, all 4 batches).
// lane: bq = lane>>4 (batch), cq = lane&15 (channel quad).
// One edge = one coalesced 512B wave-load; lane accumulates its (b, 4ch) slice.
// MFMA: M = 32 rows = (node_local*4 + b), K = 160, N = 64 — same tile as before.
template<int L0>
__global__ __launch_bounds__(512)
void layer_kernel(const u16* __restrict__ h_in,
                  const float* __restrict__ x,
                  const float* __restrict__ AXb,
                  const unsigned short* __restrict__ wf,
                  const float* __restrict__ bias,
                  const int* __restrict__ row_ptr,
                  const int2* __restrict__ csr,
                  u16* __restrict__ h_out,
                  int t)
{
    __shared__ int2 sIdx[CAP];              // 4 KB: block's contiguous csr segment
    __shared__ unsigned short sA[32*168];   // 10.5 KB: bf16 MFMA A tile

    int tid = threadIdx.x;
    int wave = tid >> 6, lane = tid & 63;
    int bq = lane >> 4, cq = lane & 15;

    int n0 = blockIdx.x * 8;                // 1250 * 8 = 10000 exact
    int estart = row_ptr[n0];
    int eend   = row_ptr[n0 + 8];
    int cnt = eend - estart; if (cnt > CAP) cnt = CAP;

    // stage csr segment (1 entry/thread; zero-fill so masked idx loads node 0)
    {
        int2 v = make_int2(0, 0);
        if (tid < cnt) v = csr[estart + tid];
        sIdx[tid] = v;
    }

    // wave's B fragments + bias
    int ct = wave & 3, rt = wave >> 2;
    const bf16x8* wfv = (const bf16x8*)wf;
    bf16x8 bfr[5];
    #pragma unroll
    for (int kt=0; kt<5; ++kt) bfr[kt] = wfv[(ct*5+kt)*64 + lane];
    float bv = bias[ct*16 + cq];            // C col = lane&15

    int n = n0 + wave;
    int bseg = row_ptr[n] - estart;
    int eseg = row_ptr[n+1] - estart;

    // direct term: full 512B node row across the wave
    ushort4 hv = *(const ushort4*)(h_in + ((size_t)n*BB + bq)*HH + cq*4);

    __syncthreads();

    float4 acc = {0.f,0.f,0.f,0.f};
    if (eseg <= cnt) {
        for (int e = bseg; e < eseg; e += 16) {
            #pragma unroll
            for (int u=0; u<16; ++u) {
                int idx = e + u;
                int2 cw = sIdx[idx & (CAP-1)];
                float w = (idx < eseg) ? __int_as_float(cw.y) : 0.f;
                ushort4 v = *(const ushort4*)(h_in + ((size_t)cw.x*BB + bq)*HH + cq*4);
                acc.x = fmaf(w, b2f(v.x), acc.x); acc.y = fmaf(w, b2f(v.y), acc.y);
                acc.z = fmaf(w, b2f(v.z), acc.z); acc.w = fmaf(w, b2f(v.w), acc.w);
            }
        }
    } else {
        // fallback: segment overflowed CAP (practically unreachable)
        for (int e = bseg; e < eseg; e += 16) {
            #pragma unroll
            for (int u=0; u<16; ++u) {
                int idx = e + u;
                int2 cw = (idx < eseg) ? csr[estart + idx] : make_int2(0,0);
                float w = (idx < eseg) ? __int_as_float(cw.y) : 0.f;
                ushort4 v = *(const ushort4*)(h_in + ((size_t)cw.x*BB + bq)*HH + cq*4);
                acc.x = fmaf(w, b2f(v.x), acc.x); acc.y = fmaf(w, b2f(v.y), acc.y);
                acc.z = fmaf(w, b2f(v.z), acc.z); acc.w = fmaf(w, b2f(v.w), acc.w);
            }
        }
    }

    // stage A tile: row = node_local*4 + b
    int rowL = wave*4 + bq;
    *(ushort4*)&sA[rowL*168 + cq*4] = hv;
    { uint2 p; p.x = pack2(acc.x, acc.y); p.y = pack2(acc.z, acc.w);
      *(uint2*)&sA[rowL*168 + 64 + cq*4] = p; }
    if (cq == 0) {
        uint2 p;
        if (L0) {
            const float2 xv = *(const float2*)(x + (((size_t)bq*TT + t)*NN + n)*DD);
            float ax0 = AXb[(size_t)n*(TD*BB) + (2*t)*BB + bq];
            float ax1 = AXb[(size_t)n*(TD*BB) + (2*t+1)*BB + bq];
            p.x = pack2(xv.x, xv.y); p.y = pack2(ax0, ax1);
        } else {
            p.x = 0u; p.y = 0u;
        }
        *(uint2*)&sA[rowL*168 + 128] = p;
    } else if (cq < 8) {
        *(uint2*)&sA[rowL*168 + 132 + (cq-1)*4] = make_uint2(0u, 0u);
    }
    __syncthreads();

    // MFMA: C-tile (rt, ct); A row = lane&15, k = (lane>>4)*8 + j
    f32x4 dacc = {0.f,0.f,0.f,0.f};
    #pragma unroll
    for (int kt=0; kt<5; ++kt) {
        bf16x8 a = *(const bf16x8*)&sA[(rt*16 + cq)*168 + kt*32 + bq*8];
        dacc = __builtin_amdgcn_mfma_f32_16x16x32_bf16(a, bfr[kt], dacc, 0, 0, 0);
    }
    #pragma unroll
    for (int i2=0;i2<4;i2++) {
        int r = rt*16 + bq*4 + i2;           // C/D: row=(lane>>4)*4+reg, col=lane&15
        int nodeL = r >> 2, bo = r & 3;
        float v = fmaxf(dacc[i2] + bv, 0.f);
        unsigned p = pack2(v, v);
        h_out[((size_t)(n0 + nodeL)*BB + bo)*HH + ct*16 + cq] = (u16)p;
    }
}

// ---------------- output ----------------
__global__ void out_kernel(const u16* __restrict__ h, const float* __restrict__ Wp,
                           const float* __restrict__ bp, float* __restrict__ outp) {
    int g = blockIdx.x*256 + threadIdx.x;
    int wave = g >> 6, lane = g & 63;
    if (wave >= BB*NN) return;
    int b = wave / NN, n = wave - b*NN;
    float v = b2f(h[((size_t)n*BB + b)*HH + lane]) * Wp[lane];
    for (int off=32; off; off>>=1) v += __shfl_down(v, off);
    v = __shfl(v, 0) + bp[0];
    if (lane < NPREDD) outp[((size_t)b*NPREDD + lane)*NN + n] = v;
}

extern "C" void kernel_launch(void* const* d_in, const int* in_sizes, int n_in,
                              void* d_out, int out_size, void* d_ws, size_t ws_size,
                              hipStream_t stream) {
    const float* x   = (const float*)d_in[0];
    const int*   ei  = (const int*)d_in[1];
    const float* ew  = (const float*)d_in[2];
    const float* W0  = (const float*)d_in[3];
    const float* b0  = (const float*)d_in[4];
    const float* W1  = (const float*)d_in[5];
    const float* b1  = (const float*)d_in[6];
    const float* Wp  = (const float*)d_in[7];
    const float* bp  = (const float*)d_in[8];
    float* outp = (float*)d_out;

    char* ws = (char*)d_ws;
    size_t off = 0;
    auto alloc = [&](size_t bytes) { void* p = ws + off; off = (off + bytes + 255) & ~(size_t)255; return p; };
    u16* h      = (u16*)alloc((size_t)NN*BB*HH*2);
    u16* h1     = (u16*)alloc((size_t)NN*BB*HH*2);
    float* xTb  = (float*)alloc(((size_t)NN*TD*BB + 64)*4);
    float* AXb  = (float*)alloc((size_t)NN*TD*BB*4);
    unsigned short* wf0 = (unsigned short*)alloc(1280*8*2);
    unsigned short* wf1 = (unsigned short*)alloc(1280*8*2);
    int2*  csr  = (int2*)alloc(((size_t)EE + 16)*8);
    int* row_ptr= (int*)alloc((NN+1)*4);
    int* deg    = (int*)alloc(NN*4);
    int* cursor = (int*)alloc(NN*4);

    const int* srcv = ei;
    const int* dstv = ei + EE;

    hipMemsetAsync(deg, 0, NN*4, stream);
    hipMemsetAsync(h, 0, (size_t)NN*BB*HH*2, stream);
    hipMemsetAsync(csr + EE, 0, 16*8, stream);

    hist_kernel<<<(EE+255)/256, 256, 0, stream>>>(dstv, deg);
    scan_kernel<<<1, 1024, 0, stream>>>(deg, row_ptr, cursor);
    fill_kernel<<<(EE+255)/256, 256, 0, stream>>>(srcv, dstv, ew, cursor, csr);
    transpose_x<<<(BB*TT*NN*DD+255)/256, 256, 0, stream>>>(x, xTb);
    ax_gather<<<(NN*64+255)/256, 256, 0, stream>>>(xTb, row_ptr, csr, AXb);
    prep_wfrag<<<10, 256, 0, stream>>>(W0, W1, wf0, wf1);

    const int grid = 1250;   // 8 nodes/block, all 4 batches fused
    for (int t=0; t<TT; ++t) {
        layer_kernel<1><<<grid, 512, 0, stream>>>(h,  x, AXb, wf0, b0, row_ptr, csr, h1, t);
        layer_kernel<0><<<grid, 512, 0, stream>>>(h1, nullptr, nullptr, wf1, b1, row_ptr, csr, h, 0);
    }
    out_kernel<<<(BB*NN*64+255)/256, 256, 0, stream>>>(h, Wp, bp, outp);
}